// Round 8
// baseline (3961.658 us; speedup 1.0000x reference)
//
#include <hip/hip_runtime.h>
#include <hip/hip_bf16.h>

// Problem constants
#define B_   64
#define T_   32
#define S_   33      // T+1 LSTM steps
#define V_   32000
#define E_   512
#define H_   1024

// ---------------------------------------------------------------------------
// Kernel 1: Xt[t][e][b] — input sequence, transposed so step-kernel reads are
// coalesced over b.  t==0 -> features; t>=1 -> W_embed[:, captions[b,t-1]] + b_embed.
// grid 33*8 blocks (t, e-group of 64) x 64 threads (lane = b).
// ---------------------------------------------------------------------------
__global__ __launch_bounds__(64) void build_xt(
    const float* __restrict__ feat,   // [B,E]
    const int*   __restrict__ caps,   // [B,T] int32 (verified r7)
    const float* __restrict__ Wemb,   // [E,V]
    const float* __restrict__ bemb,   // [E]
    float* __restrict__ Xt)           // [S][E][B]
{
    int t  = blockIdx.x >> 3;          // 0..32
    int eg = (blockIdx.x & 7) * 64;    // e-group base
    int b  = threadIdx.x;
    int cap = (t > 0) ? caps[b * T_ + (t - 1)] : 0;
    for (int i = 0; i < 64; ++i) {
        int e = eg + i;
        float x = (t == 0) ? feat[b * E_ + e]
                           : (Wemb[(size_t)e * V_ + cap] + bemb[e]);
        Xt[((size_t)t * E_ + e) * B_ + b] = x;
    }
}

// ---------------------------------------------------------------------------
// Kernel 2: transpose initial state to [j][b].
// grid 1024 blocks x 64 threads.
// ---------------------------------------------------------------------------
__global__ __launch_bounds__(64) void init_state_t(
    const float* __restrict__ h0,     // [B,H]
    const float* __restrict__ c0,     // [B,H]
    float* __restrict__ ht,           // [H][B]
    float* __restrict__ ct)           // [H][B]
{
    int j = blockIdx.x;
    int b = threadIdx.x;
    ht[j * B_ + b] = h0[b * H_ + j];
    ct[j * B_ + b] = c0[b * H_ + j];
}

// ---------------------------------------------------------------------------
// Kernel 3 (x33): pure fp32 VALU LSTM step — transliteration of the reference.
// grid 512 blocks x 64 threads.  Block bx owns hidden units {2bx, 2bx+1} for
// all 4 gates; lane = batch b.  Weights wave-uniform (scalar loads);
// activations from transposed [k][b] buffers (coalesced).
// ROUND 8: output is fp32 (the reference's dtype) — the sole change vs r5.
// ---------------------------------------------------------------------------
__global__ __launch_bounds__(64) void lstm_step_valu(
    const float* __restrict__ Xt,      // [S][E][B]
    const float* __restrict__ w_ih,    // [4H][E]
    const float* __restrict__ w_hh,    // [4H][H]
    const float* __restrict__ b_ih,    // [4H]
    const float* __restrict__ b_hh,    // [4H]
    const float* __restrict__ ht_in,   // [H][B]
    float* __restrict__ ct,            // [H][B]
    float* __restrict__ ht_out,        // [H][B]
    float* __restrict__ out,           // [B][S][H] fp32
    int t)
{
    int b  = threadIdx.x;
    int j0 = blockIdx.x * 2;

    float acc[4][2];
#pragma unroll
    for (int g = 0; g < 4; ++g)
#pragma unroll
        for (int u = 0; u < 2; ++u)
            acc[g][u] = b_ih[g * H_ + j0 + u] + b_hh[g * H_ + j0 + u];

    // x_t @ w_ih^T
    const float* xt = Xt + (size_t)t * E_ * B_;
    for (int k = 0; k < E_; ++k) {
        float xv = xt[k * B_ + b];
#pragma unroll
        for (int g = 0; g < 4; ++g)
#pragma unroll
            for (int u = 0; u < 2; ++u)
                acc[g][u] += xv * w_ih[(size_t)(g * H_ + j0 + u) * E_ + k];
    }
    // h @ w_hh^T
    for (int k = 0; k < H_; ++k) {
        float hv = ht_in[k * B_ + b];
#pragma unroll
        for (int g = 0; g < 4; ++g)
#pragma unroll
            for (int u = 0; u < 2; ++u)
                acc[g][u] += hv * w_hh[(size_t)(g * H_ + j0 + u) * H_ + k];
    }

    // gate order per reference split: i, f, g, o
#pragma unroll
    for (int u = 0; u < 2; ++u) {
        int j = j0 + u;
        float si = 1.f / (1.f + expf(-acc[0][u]));
        float sf = 1.f / (1.f + expf(-acc[1][u]));
        float tg = tanhf(acc[2][u]);
        float so = 1.f / (1.f + expf(-acc[3][u]));
        float cn = sf * ct[j * B_ + b] + si * tg;
        ct[j * B_ + b] = cn;
        float hn = so * tanhf(cn);
        ht_out[j * B_ + b] = hn;
        out[((size_t)b * S_ + t) * H_ + j] = hn;   // fp32 write
    }
}

// ---------------------------------------------------------------------------
extern "C" void kernel_launch(void* const* d_in, const int* in_sizes, int n_in,
                              void* d_out, int out_size, void* d_ws, size_t ws_size,
                              hipStream_t stream)
{
    // Positional defaults (setup_inputs dict order)...
    const float* feat = (const float*)d_in[0];
    const int*   caps = (const int*)d_in[1];
    const float* Wemb = (const float*)d_in[2];
    const float* bemb = (const float*)d_in[3];
    const float* w_ih = (const float*)d_in[4];
    const float* w_hh = (const float*)d_in[5];
    const float* b_ih = (const float*)d_in[6];
    const float* b_hh = (const float*)d_in[7];
    const float* h0   = (const float*)d_in[8];   // dict order (r6 swap exonerated)
    const float* c0   = (const float*)d_in[9];
    // ...then override by unique element counts.
    int nbias = 0, nstate = 0;
    for (int i = 0; i < n_in; ++i) {
        switch (in_sizes[i]) {
            case 64 * 512:        feat = (const float*)d_in[i]; break;   // 32768
            case 64 * 32:         caps = (const int*)d_in[i];   break;   // 2048
            case 512 * 32000:     Wemb = (const float*)d_in[i]; break;   // 16384000
            case 512:             bemb = (const float*)d_in[i]; break;
            case 4096 * 512:      w_ih = (const float*)d_in[i]; break;   // 2097152
            case 4096 * 1024:     w_hh = (const float*)d_in[i]; break;   // 4194304
            case 4096:
                if (nbias++ == 0) b_ih = (const float*)d_in[i];
                else              b_hh = (const float*)d_in[i];
                break;
            case 64 * 1024:                                              // 65536
                if (nstate++ == 0) h0 = (const float*)d_in[i];
                else               c0 = (const float*)d_in[i];
                break;
            default: break;
        }
    }
    float* out = (float*)d_out;   // fp32 output — reference's dtype

    // workspace: Xt 4.33 MB + htA/htB/ct 0.75 MB  (~5.1 MB total)
    char* ws = (char*)d_ws;
    float* Xt  = (float*)ws; ws += (size_t)S_ * E_ * B_ * 4;
    float* htA = (float*)ws; ws += (size_t)H_ * B_ * 4;
    float* htB = (float*)ws; ws += (size_t)H_ * B_ * 4;
    float* ct  = (float*)ws; ws += (size_t)H_ * B_ * 4;

    build_xt<<<S_ * 8, 64, 0, stream>>>(feat, caps, Wemb, bemb, Xt);
    init_state_t<<<H_, 64, 0, stream>>>(h0, c0, htA, ct);

    for (int t = 0; t < S_; ++t) {
        const float* ht_in  = (t & 1) ? htB : htA;
        float*       ht_out = (t & 1) ? htA : htB;
        lstm_step_valu<<<512, 64, 0, stream>>>(Xt, w_ih, w_hh, b_ih, b_hh,
                                               ht_in, ct, ht_out, out, t);
    }
}

// Round 9
// 1256.083 us; speedup vs baseline: 3.1540x; 3.1540x over previous
//
#include <hip/hip_runtime.h>
#include <hip/hip_bf16.h>

// Problem constants
#define B_   64
#define T_   32
#define S_   33      // T+1 LSTM steps
#define V_   32000
#define E_   512
#define H_   1024

typedef __attribute__((ext_vector_type(8))) short  bf16x8;
typedef __attribute__((ext_vector_type(4))) float  f32x4;

// Split fp32 into hi/lo bf16 pair: x ~= hi + lo  (error ~2^-16 rel)
__device__ inline void split2(float x, unsigned short& hi, unsigned short& lo) {
    __hip_bfloat16 h = __float2bfloat16(x);
    float r = x - __bfloat162float(h);
    __hip_bfloat16 l = __float2bfloat16(r);
    hi = *reinterpret_cast<unsigned short*>(&h);
    lo = *reinterpret_cast<unsigned short*>(&l);
}

// Load 8 contiguous fp32 and split into hi/lo bf16x8 fragments.
__device__ inline void load_f32x8_hilo(const float* __restrict__ p,
                                       bf16x8& hi, bf16x8& lo) {
    const float4* q = reinterpret_cast<const float4*>(p);
    float4 v0 = q[0], v1 = q[1];
    float f[8] = {v0.x, v0.y, v0.z, v0.w, v1.x, v1.y, v1.z, v1.w};
#pragma unroll
    for (int j = 0; j < 8; ++j) {
        unsigned short h, l; split2(f[j], h, l);
        hi[j] = (short)h; lo[j] = (short)l;
    }
}

// ---------------------------------------------------------------------------
// Kernel 1: build X[t*64+b, e]  (time-major) as hi/lo bf16.
// t==0 -> features; t>=1 -> W_embed[:, captions[b,t-1]] + b_embed.
// grid 2112 blocks x 512 threads (thread = e).
// ---------------------------------------------------------------------------
__global__ __launch_bounds__(512) void build_x(
    const float* __restrict__ feat,   // [B,E]
    const int*   __restrict__ caps,   // [B,T] int32
    const float* __restrict__ Wemb,   // [E,V]
    const float* __restrict__ bemb,   // [E]
    unsigned short* __restrict__ Xhi,
    unsigned short* __restrict__ Xlo)
{
    int row = blockIdx.x;          // t*64 + b
    int t = row >> 6, b = row & 63;
    int e = threadIdx.x;
    float x;
    if (t == 0) {
        x = feat[b * E_ + e];
    } else {
        int cap = caps[b * T_ + (t - 1)];
        x = Wemb[(size_t)e * V_ + cap] + bemb[e];
    }
    unsigned short hi, lo; split2(x, hi, lo);
    Xhi[(size_t)row * E_ + e] = hi;
    Xlo[(size_t)row * E_ + e] = lo;
}

// ---------------------------------------------------------------------------
// Kernel 2: init LSTM state.  h -> hi/lo bf16, c fp32.
// ---------------------------------------------------------------------------
__global__ __launch_bounds__(256) void init_state(
    const float* __restrict__ h0,
    const float* __restrict__ c0,
    unsigned short* __restrict__ hhi,
    unsigned short* __restrict__ hlo,
    float* __restrict__ c)
{
    int idx = blockIdx.x * 256 + threadIdx.x;
    unsigned short hi, lo; split2(h0[idx], hi, lo);
    hhi[idx] = hi;
    hlo[idx] = lo;
    c[idx]   = c0[idx];
}

// ---------------------------------------------------------------------------
// Kernel 3 (x33): MFMA LSTM step (r3 structure — math verified, fp32 out).
// gates = x_t @ w_ih^T + h @ w_hh^T + b_ih + b_hh.
// A operands staged hi/lo bf16; W read fp32 and split in-kernel; 3-term MFMA
// (ahi*bhi + alo*bhi + ahi*blo) -> ~2^-17 relative GEMM error.
// grid 256 blocks = 4 Mtiles(16 batch rows) x 64 Jtiles(16 h-cols), 4 waves;
// wave g computes gate g's 16x16 tile (K=512 for x, K=1024 for h).
// ---------------------------------------------------------------------------
__global__ __launch_bounds__(256) void lstm_step(
    const unsigned short* __restrict__ Xhi,    // [2112, 512]
    const unsigned short* __restrict__ Xlo,
    const float* __restrict__ w_ih,            // [4096, 512]
    const float* __restrict__ w_hh,            // [4096, 1024]
    const float* __restrict__ b_ih,            // [4096]
    const float* __restrict__ b_hh,            // [4096]
    const unsigned short* __restrict__ hhi_in, // [64, 1024]
    const unsigned short* __restrict__ hlo_in,
    float* __restrict__ c,                     // [64, 1024]
    unsigned short* __restrict__ hhi_out,
    unsigned short* __restrict__ hlo_out,
    float* __restrict__ out,                   // [B][S][H] fp32
    int t)
{
    int bx = blockIdx.x;
    int m0 = (bx & 3) * 16;        // batch-row tile
    int j0 = (bx >> 2) * 16;       // h-col tile
    int wave = threadIdx.x >> 6;   // gate index: 0=i 1=f 2=g 3=o
    int lane = threadIdx.x & 63;
    int lm   = lane & 15;
    int kq   = (lane >> 4) * 8;
    int nrow = wave * H_ + j0 + lm;   // row in w_ih / w_hh

    f32x4 acc = f32x4{0.f, 0.f, 0.f, 0.f};

    // x_t @ w_ih^T  (K = 512)
    for (int kk = 0; kk < E_; kk += 32) {
        bf16x8 bhi, blo;
        load_f32x8_hilo(w_ih + (size_t)nrow * E_ + kk + kq, bhi, blo);
        size_t aoff = (size_t)(t * 64 + m0 + lm) * E_ + kk + kq;
        bf16x8 ahi = *reinterpret_cast<const bf16x8*>(Xhi + aoff);
        bf16x8 alo = *reinterpret_cast<const bf16x8*>(Xlo + aoff);
        acc = __builtin_amdgcn_mfma_f32_16x16x32_bf16(ahi, bhi, acc, 0, 0, 0);
        acc = __builtin_amdgcn_mfma_f32_16x16x32_bf16(alo, bhi, acc, 0, 0, 0);
        acc = __builtin_amdgcn_mfma_f32_16x16x32_bf16(ahi, blo, acc, 0, 0, 0);
    }
    // h @ w_hh^T  (K = 1024)
    for (int kk = 0; kk < H_; kk += 32) {
        bf16x8 bhi, blo;
        load_f32x8_hilo(w_hh + (size_t)nrow * H_ + kk + kq, bhi, blo);
        size_t aoff = (size_t)(m0 + lm) * H_ + kk + kq;
        bf16x8 ahi = *reinterpret_cast<const bf16x8*>(hhi_in + aoff);
        bf16x8 alo = *reinterpret_cast<const bf16x8*>(hlo_in + aoff);
        acc = __builtin_amdgcn_mfma_f32_16x16x32_bf16(ahi, bhi, acc, 0, 0, 0);
        acc = __builtin_amdgcn_mfma_f32_16x16x32_bf16(alo, bhi, acc, 0, 0, 0);
        acc = __builtin_amdgcn_mfma_f32_16x16x32_bf16(ahi, blo, acc, 0, 0, 0);
    }

    __shared__ float gbuf[4][16][16];   // [gate][batch-row][h-col]
    int rbase = (lane >> 4) * 4;        // C/D: col=lane&15, row=(lane>>4)*4+r (verified r4 probe)
#pragma unroll
    for (int r = 0; r < 4; ++r) gbuf[wave][rbase + r][lm] = acc[r];
    __syncthreads();

    int tid = threadIdx.x;
    int m = tid >> 4, j = tid & 15;
    int b  = m0 + m;
    int jg = j0 + j;
    float iv = gbuf[0][m][j] + b_ih[0 * H_ + jg] + b_hh[0 * H_ + jg];
    float fv = gbuf[1][m][j] + b_ih[1 * H_ + jg] + b_hh[1 * H_ + jg];
    float gv = gbuf[2][m][j] + b_ih[2 * H_ + jg] + b_hh[2 * H_ + jg];
    float ov = gbuf[3][m][j] + b_ih[3 * H_ + jg] + b_hh[3 * H_ + jg];
    float si = 1.f / (1.f + expf(-iv));
    float sf = 1.f / (1.f + expf(-fv));
    float so = 1.f / (1.f + expf(-ov));
    float tg = tanhf(gv);
    size_t cidx = (size_t)b * H_ + jg;
    float cn = sf * c[cidx] + si * tg;
    c[cidx] = cn;
    float hn = so * tanhf(cn);
    unsigned short hi, lo; split2(hn, hi, lo);
    hhi_out[cidx] = hi;
    hlo_out[cidx] = lo;
    out[((size_t)b * S_ + t) * H_ + jg] = hn;   // fp32 write
}

// ---------------------------------------------------------------------------
extern "C" void kernel_launch(void* const* d_in, const int* in_sizes, int n_in,
                              void* d_out, int out_size, void* d_ws, size_t ws_size,
                              hipStream_t stream)
{
    // Positional defaults (setup_inputs dict order)...
    const float* feat = (const float*)d_in[0];
    const int*   caps = (const int*)d_in[1];
    const float* Wemb = (const float*)d_in[2];
    const float* bemb = (const float*)d_in[3];
    const float* w_ih = (const float*)d_in[4];
    const float* w_hh = (const float*)d_in[5];
    const float* b_ih = (const float*)d_in[6];
    const float* b_hh = (const float*)d_in[7];
    const float* h0   = (const float*)d_in[8];
    const float* c0   = (const float*)d_in[9];
    // ...then override by unique element counts (r5-verified consistent).
    int nbias = 0, nstate = 0;
    for (int i = 0; i < n_in; ++i) {
        switch (in_sizes[i]) {
            case 64 * 512:        feat = (const float*)d_in[i]; break;
            case 64 * 32:         caps = (const int*)d_in[i];   break;
            case 512 * 32000:     Wemb = (const float*)d_in[i]; break;
            case 512:             bemb = (const float*)d_in[i]; break;
            case 4096 * 512:      w_ih = (const float*)d_in[i]; break;
            case 4096 * 1024:     w_hh = (const float*)d_in[i]; break;
            case 4096:
                if (nbias++ == 0) b_ih = (const float*)d_in[i];
                else              b_hh = (const float*)d_in[i];
                break;
            case 64 * 1024:
                if (nstate++ == 0) h0 = (const float*)d_in[i];
                else               c0 = (const float*)d_in[i];
                break;
            default: break;
        }
    }
    float* out = (float*)d_out;   // fp32 output (r8-verified)

    // workspace: ~4.9 MB (r8-verified safe size range)
    char* ws = (char*)d_ws;
    unsigned short* Xhi  = (unsigned short*)ws; ws += (size_t)2112 * 512 * 2;
    unsigned short* Xlo  = (unsigned short*)ws; ws += (size_t)2112 * 512 * 2;
    unsigned short* hhiA = (unsigned short*)ws; ws += (size_t)B_ * H_ * 2;
    unsigned short* hloA = (unsigned short*)ws; ws += (size_t)B_ * H_ * 2;
    unsigned short* hhiB = (unsigned short*)ws; ws += (size_t)B_ * H_ * 2;
    unsigned short* hloB = (unsigned short*)ws; ws += (size_t)B_ * H_ * 2;
    float* cbuf          = (float*)ws;          ws += (size_t)B_ * H_ * 4;

    build_x<<<2112, 512, 0, stream>>>(feat, caps, Wemb, bemb, Xhi, Xlo);
    init_state<<<256, 256, 0, stream>>>(h0, c0, hhiA, hloA, cbuf);

    for (int t = 0; t < S_; ++t) {
        const unsigned short* hhi_in = (t & 1) ? hhiB : hhiA;
        const unsigned short* hlo_in = (t & 1) ? hloB : hloA;
        unsigned short* hhi_out = (t & 1) ? hhiA : hhiB;
        unsigned short* hlo_out = (t & 1) ? hloA : hloB;
        lstm_step<<<256, 256, 0, stream>>>(Xhi, Xlo, w_ih, w_hh, b_ih, b_hh,
                                           hhi_in, hlo_in, cbuf,
                                           hhi_out, hlo_out, out, t);
    }
}